// Round 12
// baseline (1789.739 us; speedup 1.0000x reference)
//
#include <hip/hip_runtime.h>
#include <hip/hip_fp16.h>
#include <math.h>

#define HID 9000
#define EMB 300
#define NSTEPS 20
#define RS 9216            // padded row stride (floats) for h0 / hist rows
#define HID8 1125          // 16B fp16 chunks per w_out/w_hh-fp16 row (9000/8)
#define EMB4 75            // 4-float4 chunks per 300-vector
#define F4_ROW 2250        // valid float4 chunks per fp32 w_hh row (9000/4)
#define QROW_DW 1152       // int4 padded row: 1152 dwords (= uint4s per group)
#define QHALF 576          // dwords per half row
#define Q_D    1.4054567378526131e-3f   // int4: (1/sqrt(9000))/7.5
#define Q_INVD 711.5124735378853f       // int4: 7.5*sqrt(9000)
#define RAWSTR 320         // float stride of one raw-accum buffer (3x rotate)

__device__ __forceinline__ float sigmoidf_(float v) {
    return 1.0f / (1.0f + expf(-v));
}

__device__ __forceinline__ float waveReduceSum(float v) {
#pragma unroll
    for (int off = 32; off > 0; off >>= 1) v += __shfl_down(v, off, 64);
    return v;
}

// decode one dword (8 int4, low nibble first) against 2 float4 of e,
// accumulating into TWO independent chains aA/aB
#define I4DOT8(d, v0, v1, aA, aB)                                      \
    {   unsigned int _d = (d);                                         \
        aA = fmaf((float)(((int)(_d << 28)) >> 28), v0.x, aA);         \
        aB = fmaf((float)(((int)(_d << 24)) >> 28), v0.y, aB);         \
        aA = fmaf((float)(((int)(_d << 20)) >> 28), v0.z, aA);         \
        aB = fmaf((float)(((int)(_d << 16)) >> 28), v0.w, aB);         \
        aA = fmaf((float)(((int)(_d << 12)) >> 28), v1.x, aA);         \
        aB = fmaf((float)(((int)(_d <<  8)) >> 28), v1.y, aB);         \
        aA = fmaf((float)(((int)(_d <<  4)) >> 28), v1.z, aA);         \
        aB = fmaf((float)(((int)(_d      )) >> 28), v1.w, aB); }

__device__ __forceinline__ unsigned int quant4(float v) {
    int q = (int)rintf(v * Q_INVD);
    q = q < -8 ? -8 : (q > 7 ? 7 : q);
    return (unsigned int)(q & 0xF);
}

// quantize 8 consecutive weights (two float4) into one dword, accumulate dot
__device__ __forceinline__ unsigned int qdot8(
    float4 a, float4 b, float4 h0v, float4 h1v, float& acc)
{
    acc = fmaf(a.x, h0v.x, acc);
    acc = fmaf(a.y, h0v.y, acc);
    acc = fmaf(a.z, h0v.z, acc);
    acc = fmaf(a.w, h0v.w, acc);
    acc = fmaf(b.x, h1v.x, acc);
    acc = fmaf(b.y, h1v.y, acc);
    acc = fmaf(b.z, h1v.z, acc);
    acc = fmaf(b.w, h1v.w, acc);
    return quant4(a.x)
         | (quant4(a.y) << 4)
         | (quant4(a.z) << 8)
         | (quant4(a.w) << 12)
         | (quant4(b.x) << 16)
         | (quant4(b.y) << 20)
         | (quant4(b.z) << 24)
         | (quant4(b.w) << 28);
}

// ---------------------------------------------------------------------------
// fp32 -> fp16 weight compression (w_ih, w_out).
// ---------------------------------------------------------------------------
__global__ __launch_bounds__(256) void f32_to_f16_kernel(
    const float* __restrict__ src, __half* __restrict__ dst, int n8)
{
    int i = blockIdx.x * blockDim.x + threadIdx.x;
    const int stride = gridDim.x * blockDim.x;
    const float4* __restrict__ s4 = (const float4*)src;
    float4* __restrict__ d4 = (float4*)dst;
    for (; i < n8; i += stride) {
        float4 a = s4[2 * i];
        float4 b = s4[2 * i + 1];
        float4 o;
        ((__half2*)&o)[0] = __floats2half2_rn(a.x, a.y);
        ((__half2*)&o)[1] = __floats2half2_rn(a.z, a.w);
        ((__half2*)&o)[2] = __floats2half2_rn(b.x, b.y);
        ((__half2*)&o)[3] = __floats2half2_rn(b.z, b.w);
        d4[i] = o;
    }
}

// ---------------------------------------------------------------------------
// w_out^T (fp16): wout_t[k*300 + i] = w_out[i*HID + k]. Block = k.
// ---------------------------------------------------------------------------
__global__ __launch_bounds__(256) void woutT_kernel(
    const float* __restrict__ w_out, __half* __restrict__ wout_t)
{
    const int k = blockIdx.x;
    for (int i = threadIdx.x; i < EMB; i += 256)
        wout_t[(size_t)k * EMB + i] = __float2half(w_out[(size_t)i * HID + k]);
}

// ---------------------------------------------------------------------------
// wib[row] = w_ih[row,:] @ b_out  (fp16 w_ih copy, fp32 accumulate)
// ---------------------------------------------------------------------------
__global__ __launch_bounds__(256) void wib_kernel(
    const __half* __restrict__ wih, const float* __restrict__ b_out,
    float* __restrict__ wib, int nrows)
{
    const int row = blockIdx.x * blockDim.x + threadIdx.x;
    if (row >= nrows) return;
    const float2* __restrict__ wr = (const float2*)(wih + (size_t)row * EMB);
    const float4* __restrict__ b4 = (const float4*)b_out;
    float acc = 0.0f;
    for (int k = 0; k < EMB4; ++k) {
        float2 wv = wr[k];
        const __half2* wh = (const __half2*)&wv;
        float2 w0 = __half22float2(wh[0]);
        float2 w1 = __half22float2(wh[1]);
        float4 bv = b4[k];
        acc = fmaf(w0.x, bv.x, acc);
        acc = fmaf(w0.y, bv.y, acc);
        acc = fmaf(w1.x, bv.z, acc);
        acc = fmaf(w1.y, bv.w, acc);
    }
    wib[row] = acc;
}

// ---------------------------------------------------------------------------
// Priming step (fp16 w_ih): h0,c = lstm_cell(x, 0, 0).
// Extra blocks zero hist-row pads and raw-accum buffer 0 / S3[0].
// ---------------------------------------------------------------------------
__global__ __launch_bounds__(256) void prime_kernel_h(
    const float* __restrict__ x, const __half* __restrict__ w_ih,
    const float* __restrict__ b_ih, const float* __restrict__ b_hh,
    float* __restrict__ h, float* __restrict__ c, float* __restrict__ hist,
    float* __restrict__ raw0, float* __restrict__ S30)
{
    const int j = blockIdx.x;
    const int wave = threadIdx.x >> 6;
    const int lane = threadIdx.x & 63;
    const int row = j + wave * HID;
    const float2* __restrict__ wr = (const float2*)(w_ih + (size_t)row * EMB);
    const float4* __restrict__ x4 = (const float4*)x;
    float acc = 0.0f;
    for (int k = lane; k < EMB4; k += 64) {
        float2 wv = wr[k];
        const __half2* wh = (const __half2*)&wv;
        float2 w0 = __half22float2(wh[0]);
        float2 w1 = __half22float2(wh[1]);
        float4 xv = x4[k];
        acc = fmaf(w0.x, xv.x, acc);
        acc = fmaf(w0.y, xv.y, acc);
        acc = fmaf(w1.x, xv.z, acc);
        acc = fmaf(w1.y, xv.w, acc);
    }
    acc = waveReduceSum(acc);
    __shared__ float gl[4];
    if (lane == 0) gl[wave] = acc + b_ih[row] + b_hh[row];
    __syncthreads();
    if (threadIdx.x == 0) {
        float gi = gl[0], gg = gl[2], go = gl[3];
        float cn = sigmoidf_(gi) * tanhf(gg);
        float hn = sigmoidf_(go) * tanhf(cn);
        c[j] = cn;
        h[j] = hn;
    }
    if (blockIdx.x == 0 && threadIdx.x < RS - HID) h[HID + threadIdx.x] = 0.0f;
    if (blockIdx.x >= 1 && blockIdx.x <= NSTEPS && threadIdx.x < RS - HID)
        hist[(size_t)(blockIdx.x - 1) * RS + HID + threadIdx.x] = 0.0f;
    if (blockIdx.x == NSTEPS + 1) {
        for (int z = threadIdx.x; z < RAWSTR; z += 256) raw0[z] = 0.0f;
        if (threadIdx.x == 0) S30[0] = 0.0f;
    }
}

// ---------------------------------------------------------------------------
// ovec[i] = (sum_k e_k * w_out[i,k]) / S + b_out[i]   (fp16 w_out)
// Used only for t=0 (sOverride=1, raw h input).
// ---------------------------------------------------------------------------
__global__ __launch_bounds__(256) void outvec_kernel_h(
    const float* __restrict__ h, const __half* __restrict__ w_out,
    const float* __restrict__ b_out, float* __restrict__ ovec, float sOverride)
{
    const int i = blockIdx.x;
    const float4* __restrict__ wr = (const float4*)(w_out + (size_t)i * HID);
    const float4* __restrict__ h4 = (const float4*)h;
    const bool selfS = sOverride <= 0.0f;
    float acc = 0.0f, se = 0.0f;
    for (int k = threadIdx.x; k < HID8; k += 256) {
        float4 wv = wr[k];
        const __half2* wh = (const __half2*)&wv;
        float4 ha = h4[2 * k];
        float4 hb = h4[2 * k + 1];
        if (selfS)
            se += ((ha.x + ha.y) + (ha.z + ha.w)) + ((hb.x + hb.y) + (hb.z + hb.w));
        float2 w0 = __half22float2(wh[0]);
        float2 w1 = __half22float2(wh[1]);
        float2 w2 = __half22float2(wh[2]);
        float2 w3 = __half22float2(wh[3]);
        acc = fmaf(w0.x, ha.x, acc);
        acc = fmaf(w0.y, ha.y, acc);
        acc = fmaf(w1.x, ha.z, acc);
        acc = fmaf(w1.y, ha.w, acc);
        acc = fmaf(w2.x, hb.x, acc);
        acc = fmaf(w2.y, hb.y, acc);
        acc = fmaf(w3.x, hb.z, acc);
        acc = fmaf(w3.y, hb.w, acc);
    }
    acc = waveReduceSum(acc);
    se = waveReduceSum(se);
    __shared__ float r1[4], r2[4];
    const int wave = threadIdx.x >> 6;
    const int lane = threadIdx.x & 63;
    if (lane == 0) { r1[wave] = acc; r2[wave] = se; }
    __syncthreads();
    if (threadIdx.x == 0) {
        float S = selfS ? ((r2[0] + r2[1]) + (r2[2] + r2[3])) : sOverride;
        ovec[i] = ((r1[0] + r1[1]) + (r1[2] + r1[3])) / S + b_out[i];
    }
}

// ---------------------------------------------------------------------------
// Fused t=0: exact fp32 w_hh GEMV + int4 quantize (4-j interleaved layout)
// + epilogue: c update, e0 -> hist row 0, ACCUMULATE raw_out/S_out (for t=1),
// block 0 zeroes the t=2 rotation buffer.
// ---------------------------------------------------------------------------
__global__ __launch_bounds__(256) void convgates_q4i4f(
    const float* __restrict__ h, const float* __restrict__ ovec,
    const float* __restrict__ w_hh, uint4* __restrict__ whh4i,
    const __half* __restrict__ w_ih, const __half* __restrict__ wout_t,
    const float* __restrict__ b_ih, const float* __restrict__ b_hh,
    float* __restrict__ c, float* __restrict__ e_out,
    float* __restrict__ raw_out, float* __restrict__ S_out,
    float* __restrict__ zero_buf, float* __restrict__ zero_S)
{
    const int jq = blockIdx.x;
    const int j0 = jq * 4;
    const int wave = threadIdx.x >> 6;
    const int lane = threadIdx.x & 63;
    const int pair = wave >> 1;
    const int half = wave & 1;

    if (blockIdx.x == 0) {
        for (int z = threadIdx.x; z < RAWSTR; z += 256) zero_buf[z] = 0.0f;
        if (threadIdx.x == 0) *zero_S = 0.0f;
    }

    const float4* __restrict__ wA0 =
        (const float4*)(w_hh + (size_t)(2 * pair * HID + j0) * HID);
    const float4* __restrict__ wA1 = wA0 + F4_ROW;
    const float4* __restrict__ wA2 = wA1 + F4_ROW;
    const float4* __restrict__ wA3 = wA2 + F4_ROW;
    const float4* __restrict__ wB0 =
        (const float4*)(w_hh + (size_t)((2 * pair + 1) * HID + j0) * HID);
    const float4* __restrict__ wB1 = wB0 + F4_ROW;
    const float4* __restrict__ wB2 = wB1 + F4_ROW;
    const float4* __restrict__ wB3 = wB2 + F4_ROW;
    uint4* __restrict__ dst0 = whh4i + (size_t)(jq * 4 + pair * 2 + 0) * QROW_DW;
    uint4* __restrict__ dst1 = whh4i + (size_t)(jq * 4 + pair * 2 + 1) * QROW_DW;
    const float4* __restrict__ h4 = (const float4*)h;

    float aA0 = 0.0f, aA1 = 0.0f, aA2 = 0.0f, aA3 = 0.0f;
    float aB0 = 0.0f, aB1 = 0.0f, aB2 = 0.0f, aB3 = 0.0f;
    const int base = half * QHALF;
    for (int it = 0; it < 9; ++it) {
        const int ci = base + it * 64 + lane;
        uint4 p0, p1;
        p0.x = p0.y = p0.z = p0.w = 0u;
        p1.x = p1.y = p1.z = p1.w = 0u;
        if (ci < HID8) {
            float4 hv0 = h4[2 * ci];
            float4 hv1 = h4[2 * ci + 1];
            p0.x = qdot8(wA0[2 * ci], wA0[2 * ci + 1], hv0, hv1, aA0);
            p0.y = qdot8(wA1[2 * ci], wA1[2 * ci + 1], hv0, hv1, aA1);
            p0.z = qdot8(wA2[2 * ci], wA2[2 * ci + 1], hv0, hv1, aA2);
            p0.w = qdot8(wA3[2 * ci], wA3[2 * ci + 1], hv0, hv1, aA3);
            p1.x = qdot8(wB0[2 * ci], wB0[2 * ci + 1], hv0, hv1, aB0);
            p1.y = qdot8(wB1[2 * ci], wB1[2 * ci + 1], hv0, hv1, aB1);
            p1.z = qdot8(wB2[2 * ci], wB2[2 * ci + 1], hv0, hv1, aB2);
            p1.w = qdot8(wB3[2 * ci], wB3[2 * ci + 1], hv0, hv1, aB3);
        }
        dst0[ci] = p0;
        dst1[ci] = p1;
    }

    // w_ih (fp16) @ ovec (normalized, includes b_out) for gate = wave, 4 j
    const int row0 = j0 + wave * HID;
    float ai0 = 0.0f, ai1 = 0.0f, ai2 = 0.0f, ai3 = 0.0f;
    const float2* __restrict__ wir0 = (const float2*)(w_ih + (size_t)row0 * EMB);
    const float2* __restrict__ wir1 = wir0 + EMB / 2;
    const float2* __restrict__ wir2 = wir1 + EMB / 2;
    const float2* __restrict__ wir3 = wir2 + EMB / 2;
    const float4* __restrict__ o4 = (const float4*)ovec;
    for (int k = lane; k < EMB4; k += 64) {
        float4 ov = o4[k];
        float2 wv0 = wir0[k];
        float2 wv1 = wir1[k];
        float2 wv2 = wir2[k];
        float2 wv3 = wir3[k];
        const __half2* q0 = (const __half2*)&wv0;
        const __half2* q1 = (const __half2*)&wv1;
        const __half2* q2 = (const __half2*)&wv2;
        const __half2* q3 = (const __half2*)&wv3;
        float2 a0 = __half22float2(q0[0]), a1 = __half22float2(q0[1]);
        float2 b0 = __half22float2(q1[0]), b1 = __half22float2(q1[1]);
        float2 c0 = __half22float2(q2[0]), c1 = __half22float2(q2[1]);
        float2 d0 = __half22float2(q3[0]), d1 = __half22float2(q3[1]);
        ai0 = fmaf(a0.x, ov.x, ai0); ai0 = fmaf(a0.y, ov.y, ai0);
        ai0 = fmaf(a1.x, ov.z, ai0); ai0 = fmaf(a1.y, ov.w, ai0);
        ai1 = fmaf(b0.x, ov.x, ai1); ai1 = fmaf(b0.y, ov.y, ai1);
        ai1 = fmaf(b1.x, ov.z, ai1); ai1 = fmaf(b1.y, ov.w, ai1);
        ai2 = fmaf(c0.x, ov.x, ai2); ai2 = fmaf(c0.y, ov.y, ai2);
        ai2 = fmaf(c1.x, ov.z, ai2); ai2 = fmaf(c1.y, ov.w, ai2);
        ai3 = fmaf(d0.x, ov.x, ai3); ai3 = fmaf(d0.y, ov.y, ai3);
        ai3 = fmaf(d1.x, ov.z, ai3); ai3 = fmaf(d1.y, ov.w, ai3);
    }

    aA0 = waveReduceSum(aA0); aA1 = waveReduceSum(aA1);
    aA2 = waveReduceSum(aA2); aA3 = waveReduceSum(aA3);
    aB0 = waveReduceSum(aB0); aB1 = waveReduceSum(aB1);
    aB2 = waveReduceSum(aB2); aB3 = waveReduceSum(aB3);
    ai0 = waveReduceSum(ai0); ai1 = waveReduceSum(ai1);
    ai2 = waveReduceSum(ai2); ai3 = waveReduceSum(ai3);

    __shared__ float gq[4][4][2];
    __shared__ float gih[4][4];
    __shared__ float esh[4];
    if (lane == 0) {
        gq[wave][0][0] = aA0; gq[wave][1][0] = aA1;
        gq[wave][2][0] = aA2; gq[wave][3][0] = aA3;
        gq[wave][0][1] = aB0; gq[wave][1][1] = aB1;
        gq[wave][2][1] = aB2; gq[wave][3][1] = aB3;
        gih[wave][0] = ai0 + b_ih[row0] + b_hh[row0];
        gih[wave][1] = ai1 + b_ih[row0 + 1] + b_hh[row0 + 1];
        gih[wave][2] = ai2 + b_ih[row0 + 2] + b_hh[row0 + 2];
        gih[wave][3] = ai3 + b_ih[row0 + 3] + b_hh[row0 + 3];
    }
    __syncthreads();
    if (threadIdx.x < 4) {
        const int jj = threadIdx.x;
        const int j = j0 + jj;
        float gi = (gq[0][jj][0] + gq[1][jj][0]) + gih[0][jj];
        float gf = (gq[0][jj][1] + gq[1][jj][1]) + gih[1][jj];
        float gg = (gq[2][jj][0] + gq[3][jj][0]) + gih[2][jj];
        float go = (gq[2][jj][1] + gq[3][jj][1]) + gih[3][jj];
        float cp = c[j];
        float cn = sigmoidf_(gf) * cp + sigmoidf_(gi) * tanhf(gg);
        float hn = sigmoidf_(go) * tanhf(cn);
        c[j] = cn;
        float e = expf(hn);
        e_out[j] = e;
        esh[jj] = e;
    }
    __syncthreads();
    {
        const float e0 = esh[0], e1 = esh[1], e2 = esh[2], e3 = esh[3];
        const __half* __restrict__ wt = wout_t + (size_t)j0 * EMB;
        for (int i = threadIdx.x; i < EMB; i += 256) {
            float p = __half2float(wt[i]) * e0
                    + __half2float(wt[EMB + i]) * e1
                    + __half2float(wt[2 * EMB + i]) * e2
                    + __half2float(wt[3 * EMB + i]) * e3;
            atomicAdd(&raw_out[i], p);
        }
        if (threadIdx.x == 0) atomicAdd(S_out, (e0 + e1) + (e2 + e3));
    }
}

// ---------------------------------------------------------------------------
// Steady-state fused gates (t>=1): 4-j interleaved int4 w_hh.
// Reads raw_in/S_in (accumulated by step t-1); epilogue accumulates
// raw_out/S_out for step t+1; block 0 zeroes the t+2 rotation buffer.
// gate = (gq*Q_D + w_ih@raw_in)/S + wib[row] + b_ih + b_hh.
// ---------------------------------------------------------------------------
__global__ __launch_bounds__(256) void gates_q4i4f(
    const float* __restrict__ e_in,
    const float* __restrict__ raw_in, const float* __restrict__ S_in,
    const uint4* __restrict__ whh4i, const __half* __restrict__ w_ih,
    const __half* __restrict__ wout_t, const float* __restrict__ wib,
    const float* __restrict__ b_ih, const float* __restrict__ b_hh,
    float* __restrict__ c, float* __restrict__ e_out,
    float* __restrict__ raw_out, float* __restrict__ S_out,
    float* __restrict__ zero_buf, float* __restrict__ zero_S,
    float* __restrict__ Svec, int tm1)
{
    const int jq = blockIdx.x;
    const int j0 = jq * 4;
    const int wave = threadIdx.x >> 6;
    const int lane = threadIdx.x & 63;
    const int pair = wave >> 1;
    const int half = wave & 1;

    if (blockIdx.x == 0) {
        for (int z = threadIdx.x; z < RAWSTR; z += 256) zero_buf[z] = 0.0f;
        if (threadIdx.x == 0) *zero_S = 0.0f;
    }

    const uint4* __restrict__ g0 = whh4i + (size_t)(jq * 4 + pair * 2 + 0) * QROW_DW;
    const uint4* __restrict__ g1 = whh4i + (size_t)(jq * 4 + pair * 2 + 1) * QROW_DW;
    const float4* __restrict__ e4 = (const float4*)e_in;

    float A0a = 0.0f, A0b = 0.0f, A1a = 0.0f, A1b = 0.0f;
    float A2a = 0.0f, A2b = 0.0f, A3a = 0.0f, A3b = 0.0f;
    float B0a = 0.0f, B0b = 0.0f, B1a = 0.0f, B1b = 0.0f;
    float B2a = 0.0f, B2b = 0.0f, B3a = 0.0f, B3b = 0.0f;
    const int base = half * QHALF;
#pragma unroll 3
    for (int it = 0; it < 9; ++it) {
        const int ci = base + it * 64 + lane;
        uint4 w0 = g0[ci];
        uint4 w1 = g1[ci];
        float4 ev0 = e4[2 * ci];
        float4 ev1 = e4[2 * ci + 1];
        I4DOT8(w0.x, ev0, ev1, A0a, A0b);
        I4DOT8(w0.y, ev0, ev1, A1a, A1b);
        I4DOT8(w0.z, ev0, ev1, A2a, A2b);
        I4DOT8(w0.w, ev0, ev1, A3a, A3b);
        I4DOT8(w1.x, ev0, ev1, B0a, B0b);
        I4DOT8(w1.y, ev0, ev1, B1a, B1b);
        I4DOT8(w1.z, ev0, ev1, B2a, B2b);
        I4DOT8(w1.w, ev0, ev1, B3a, B3b);
    }
    float pA0 = A0a + A0b, pA1 = A1a + A1b, pA2 = A2a + A2b, pA3 = A3a + A3b;
    float pB0 = B0a + B0b, pB1 = B1a + B1b, pB2 = B2a + B2b, pB3 = B3a + B3b;

    // w_ih (fp16) @ raw_in for THIS wave's gate (gate index == wave), 4 j
    const int row0 = j0 + wave * HID;
    float ai0 = 0.0f, ai1 = 0.0f, ai2 = 0.0f, ai3 = 0.0f;
    const float2* __restrict__ wir0 = (const float2*)(w_ih + (size_t)row0 * EMB);
    const float2* __restrict__ wir1 = wir0 + EMB / 2;
    const float2* __restrict__ wir2 = wir1 + EMB / 2;
    const float2* __restrict__ wir3 = wir2 + EMB / 2;
    const float4* __restrict__ o4 = (const float4*)raw_in;
    for (int k = lane; k < EMB4; k += 64) {
        float4 ov = o4[k];
        float2 wv0 = wir0[k];
        float2 wv1 = wir1[k];
        float2 wv2 = wir2[k];
        float2 wv3 = wir3[k];
        const __half2* q0 = (const __half2*)&wv0;
        const __half2* q1 = (const __half2*)&wv1;
        const __half2* q2 = (const __half2*)&wv2;
        const __half2* q3 = (const __half2*)&wv3;
        float2 a0 = __half22float2(q0[0]), a1 = __half22float2(q0[1]);
        float2 b0 = __half22float2(q1[0]), b1 = __half22float2(q1[1]);
        float2 c0 = __half22float2(q2[0]), c1 = __half22float2(q2[1]);
        float2 d0 = __half22float2(q3[0]), d1 = __half22float2(q3[1]);
        ai0 = fmaf(a0.x, ov.x, ai0); ai0 = fmaf(a0.y, ov.y, ai0);
        ai0 = fmaf(a1.x, ov.z, ai0); ai0 = fmaf(a1.y, ov.w, ai0);
        ai1 = fmaf(b0.x, ov.x, ai1); ai1 = fmaf(b0.y, ov.y, ai1);
        ai1 = fmaf(b1.x, ov.z, ai1); ai1 = fmaf(b1.y, ov.w, ai1);
        ai2 = fmaf(c0.x, ov.x, ai2); ai2 = fmaf(c0.y, ov.y, ai2);
        ai2 = fmaf(c1.x, ov.z, ai2); ai2 = fmaf(c1.y, ov.w, ai2);
        ai3 = fmaf(d0.x, ov.x, ai3); ai3 = fmaf(d0.y, ov.y, ai3);
        ai3 = fmaf(d1.x, ov.z, ai3); ai3 = fmaf(d1.y, ov.w, ai3);
    }

    pA0 = waveReduceSum(pA0); pA1 = waveReduceSum(pA1);
    pA2 = waveReduceSum(pA2); pA3 = waveReduceSum(pA3);
    pB0 = waveReduceSum(pB0); pB1 = waveReduceSum(pB1);
    pB2 = waveReduceSum(pB2); pB3 = waveReduceSum(pB3);
    ai0 = waveReduceSum(ai0); ai1 = waveReduceSum(ai1);
    ai2 = waveReduceSum(ai2); ai3 = waveReduceSum(ai3);

    __shared__ float gq[4][4][2];   // [wave][jj][g01] int4-dot partials
    __shared__ float gihr[4][4];    // [gate][jj] raw w_ih dot (unnormalized)
    __shared__ float esh[4];
    if (lane == 0) {
        gq[wave][0][0] = pA0; gq[wave][1][0] = pA1;
        gq[wave][2][0] = pA2; gq[wave][3][0] = pA3;
        gq[wave][0][1] = pB0; gq[wave][1][1] = pB1;
        gq[wave][2][1] = pB2; gq[wave][3][1] = pB3;
        gihr[wave][0] = ai0;
        gihr[wave][1] = ai1;
        gihr[wave][2] = ai2;
        gihr[wave][3] = ai3;
    }
    __syncthreads();
    if (threadIdx.x < 4) {
        const int jj = threadIdx.x;
        const int j = j0 + jj;
        const float S = S_in[0];
        const float invS = 1.0f / S;
        float gi = ((gq[0][jj][0] + gq[1][jj][0]) * Q_D + gihr[0][jj]) * invS
                 + wib[j] + b_ih[j] + b_hh[j];
        float gf = ((gq[0][jj][1] + gq[1][jj][1]) * Q_D + gihr[1][jj]) * invS
                 + wib[j + HID] + b_ih[j + HID] + b_hh[j + HID];
        float gg = ((gq[2][jj][0] + gq[3][jj][0]) * Q_D + gihr[2][jj]) * invS
                 + wib[j + 2 * HID] + b_ih[j + 2 * HID] + b_hh[j + 2 * HID];
        float go = ((gq[2][jj][1] + gq[3][jj][1]) * Q_D + gihr[3][jj]) * invS
                 + wib[j + 3 * HID] + b_ih[j + 3 * HID] + b_hh[j + 3 * HID];
        float cp = c[j];
        float cn = sigmoidf_(gf) * cp + sigmoidf_(gi) * tanhf(gg);
        float hn = sigmoidf_(go) * tanhf(cn);
        c[j] = cn;
        float e = expf(hn);
        e_out[j] = e;
        esh[jj] = e;
        if (blockIdx.x == 0 && jj == 0) Svec[tm1] = S;
    }
    __syncthreads();
    {
        const float e0 = esh[0], e1 = esh[1], e2 = esh[2], e3 = esh[3];
        const __half* __restrict__ wt = wout_t + (size_t)j0 * EMB;
        for (int i = threadIdx.x; i < EMB; i += 256) {
            float p = __half2float(wt[i]) * e0
                    + __half2float(wt[EMB + i]) * e1
                    + __half2float(wt[2 * EMB + i]) * e2
                    + __half2float(wt[3 * EMB + i]) * e3;
            atomicAdd(&raw_out[i], p);
        }
        if (threadIdx.x == 0) atomicAdd(S_out, (e0 + e1) + (e2 + e3));
    }
}

// ---------------------------------------------------------------------------
// Final: compute S_19, then outp[k*NSTEPS+t] = hist[t][k] / S_t (coalesced).
// ---------------------------------------------------------------------------
__global__ __launch_bounds__(1024) void final_kernel(
    const float* __restrict__ hist, const float* __restrict__ Svec,
    float* __restrict__ outp)
{
    __shared__ float red[16];
    __shared__ float invSl[NSTEPS];
    const int tid = threadIdx.x;
    const int wave = tid >> 6;
    const int lane = tid & 63;

    float s = 0.0f;
    for (int k = tid; k < HID; k += 1024) s += hist[(size_t)(NSTEPS - 1) * RS + k];
    s = waveReduceSum(s);
    if (lane == 0) red[wave] = s;
    __syncthreads();
    if (tid == 0) {
        float s19 = 0.0f;
        for (int i = 0; i < 16; i++) s19 += red[i];
        red[0] = s19;
    }
    __syncthreads();
    if (tid < NSTEPS) invSl[tid] = 1.0f / ((tid == NSTEPS - 1) ? red[0] : Svec[tid]);
    __syncthreads();

    for (int k = tid; k < HID; k += 1024) {
        float o[NSTEPS];
#pragma unroll
        for (int t = 0; t < NSTEPS; t++) o[t] = hist[(size_t)t * RS + k] * invSl[t];
        float4* dst = (float4*)(outp + (size_t)k * NSTEPS);
#pragma unroll
        for (int q = 0; q < 5; q++)
            dst[q] = make_float4(o[4 * q], o[4 * q + 1], o[4 * q + 2], o[4 * q + 3]);
    }
}

// ===========================================================================
// fp16 / fp32 fallback kernels
// ===========================================================================
__global__ __launch_bounds__(256) void gates_kernel_h(
    const float* __restrict__ h, const float* __restrict__ ovec,
    const __half* __restrict__ w_hh, const __half* __restrict__ w_ih,
    const float* __restrict__ b_ih, const float* __restrict__ b_hh,
    float* __restrict__ c, float* __restrict__ h_raw)
{
    const int j = blockIdx.x;
    const int wave = threadIdx.x >> 6;
    const int lane = threadIdx.x & 63;
    const int row = j + wave * HID;

    const float4* __restrict__ wr = (const float4*)(w_hh + (size_t)row * HID);
    const float4* __restrict__ h4 = (const float4*)h;
    float acc = 0.0f;
    for (int k = lane; k < HID8; k += 64) {
        float4 wv = wr[k];
        const __half2* wh = (const __half2*)&wv;
        float4 ha = h4[2 * k];
        float4 hb = h4[2 * k + 1];
        float2 w0 = __half22float2(wh[0]);
        float2 w1 = __half22float2(wh[1]);
        float2 w2 = __half22float2(wh[2]);
        float2 w3 = __half22float2(wh[3]);
        acc = fmaf(w0.x, ha.x, acc);
        acc = fmaf(w0.y, ha.y, acc);
        acc = fmaf(w1.x, ha.z, acc);
        acc = fmaf(w1.y, ha.w, acc);
        acc = fmaf(w2.x, hb.x, acc);
        acc = fmaf(w2.y, hb.y, acc);
        acc = fmaf(w3.x, hb.z, acc);
        acc = fmaf(w3.y, hb.w, acc);
    }
    const float2* __restrict__ wir = (const float2*)(w_ih + (size_t)row * EMB);
    const float4* __restrict__ o4 = (const float4*)ovec;
    for (int k = lane; k < EMB4; k += 64) {
        float2 wv = wir[k];
        const __half2* wh = (const __half2*)&wv;
        float2 w0 = __half22float2(wh[0]);
        float2 w1 = __half22float2(wh[1]);
        float4 ov = o4[k];
        acc = fmaf(w0.x, ov.x, acc);
        acc = fmaf(w0.y, ov.y, acc);
        acc = fmaf(w1.x, ov.z, acc);
        acc = fmaf(w1.y, ov.w, acc);
    }
    acc = waveReduceSum(acc);
    __shared__ float gl[4];
    if (lane == 0) gl[wave] = acc + b_ih[row] + b_hh[row];
    __syncthreads();
    if (threadIdx.x == 0) {
        float gi = gl[0], gf = gl[1], gg = gl[2], go = gl[3];
        float cp = c[j];
        float cn = sigmoidf_(gf) * cp + sigmoidf_(gi) * tanhf(gg);
        float hn = sigmoidf_(go) * tanhf(cn);
        c[j] = cn;
        h_raw[j] = hn;
    }
}

__global__ __launch_bounds__(256) void prime_kernel(
    const float* __restrict__ x, const float* __restrict__ w_ih,
    const float* __restrict__ b_ih, const float* __restrict__ b_hh,
    float* __restrict__ h, float* __restrict__ c)
{
    const int j = blockIdx.x;
    const int wave = threadIdx.x >> 6;
    const int lane = threadIdx.x & 63;
    const int row = j + wave * HID;
    const float4* __restrict__ wr = (const float4*)(w_ih + (size_t)row * EMB);
    const float4* __restrict__ x4 = (const float4*)x;
    float acc = 0.0f;
    for (int k = lane; k < EMB / 4; k += 64) {
        float4 w = wr[k];
        float4 xv = x4[k];
        acc = fmaf(w.x, xv.x, acc);
        acc = fmaf(w.y, xv.y, acc);
        acc = fmaf(w.z, xv.z, acc);
        acc = fmaf(w.w, xv.w, acc);
    }
    acc = waveReduceSum(acc);
    __shared__ float gl[4];
    if (lane == 0) gl[wave] = acc + b_ih[row] + b_hh[row];
    __syncthreads();
    if (threadIdx.x == 0) {
        float gi = gl[0], gg = gl[2], go = gl[3];
        float cn = sigmoidf_(gi) * tanhf(gg);
        float hn = sigmoidf_(go) * tanhf(cn);
        c[j] = cn;
        h[j] = hn;
    }
    if (blockIdx.x == 0 && threadIdx.x < RS - HID) h[HID + threadIdx.x] = 0.0f;
}

__global__ __launch_bounds__(256) void outvec_kernel(
    const float* __restrict__ h, const float* __restrict__ w_out,
    const float* __restrict__ b_out, float* __restrict__ ovec)
{
    const int i = blockIdx.x;
    const float4* __restrict__ wr = (const float4*)(w_out + (size_t)i * HID);
    const float4* __restrict__ h4 = (const float4*)h;
    float acc = 0.0f;
    for (int k = threadIdx.x; k < HID / 4; k += 256) {
        float4 w = wr[k];
        float4 hv = h4[k];
        acc = fmaf(w.x, hv.x, acc);
        acc = fmaf(w.y, hv.y, acc);
        acc = fmaf(w.z, hv.z, acc);
        acc = fmaf(w.w, hv.w, acc);
    }
    acc = waveReduceSum(acc);
    __shared__ float red[4];
    const int wave = threadIdx.x >> 6;
    const int lane = threadIdx.x & 63;
    if (lane == 0) red[wave] = acc;
    __syncthreads();
    if (threadIdx.x == 0)
        ovec[i] = red[0] + red[1] + red[2] + red[3] + b_out[i];
}

__global__ __launch_bounds__(256) void gates_kernel(
    const float* __restrict__ h, const float* __restrict__ ovec,
    const float* __restrict__ w_hh, const float* __restrict__ w_ih,
    const float* __restrict__ b_ih, const float* __restrict__ b_hh,
    float* __restrict__ c, float* __restrict__ h_raw)
{
    const int j = blockIdx.x;
    const int wave = threadIdx.x >> 6;
    const int lane = threadIdx.x & 63;
    const int row = j + wave * HID;

    const float4* __restrict__ wr = (const float4*)(w_hh + (size_t)row * HID);
    const float4* __restrict__ h4 = (const float4*)h;
    float acc = 0.0f;
    for (int k = lane; k < HID / 4; k += 64) {
        float4 w = wr[k];
        float4 hv = h4[k];
        acc = fmaf(w.x, hv.x, acc);
        acc = fmaf(w.y, hv.y, acc);
        acc = fmaf(w.z, hv.z, acc);
        acc = fmaf(w.w, hv.w, acc);
    }
    const float4* __restrict__ wir = (const float4*)(w_ih + (size_t)row * EMB);
    const float4* __restrict__ o4 = (const float4*)ovec;
    for (int k = lane; k < EMB / 4; k += 64) {
        float4 w = wir[k];
        float4 ov = o4[k];
        acc = fmaf(w.x, ov.x, acc);
        acc = fmaf(w.y, ov.y, acc);
        acc = fmaf(w.z, ov.z, acc);
        acc = fmaf(w.w, ov.w, acc);
    }
    acc = waveReduceSum(acc);
    __shared__ float gl[4];
    if (lane == 0) gl[wave] = acc + b_ih[row] + b_hh[row];
    __syncthreads();
    if (threadIdx.x == 0) {
        float gi = gl[0], gf = gl[1], gg = gl[2], go = gl[3];
        float cp = c[j];
        float cn = sigmoidf_(gf) * cp + sigmoidf_(gi) * tanhf(gg);
        float hn = sigmoidf_(go) * tanhf(cn);
        c[j] = cn;
        h_raw[j] = hn;
    }
}

__global__ __launch_bounds__(1024) void softmax_kernel(
    const float* __restrict__ h_raw, float* __restrict__ h,
    float* __restrict__ outp, int t)
{
    __shared__ float red[16];
    __shared__ float bcast;
    const int tid = threadIdx.x;
    const int wave = tid >> 6;
    const int lane = tid & 63;

    float m = -INFINITY;
    for (int k = tid; k < HID; k += 1024) m = fmaxf(m, h_raw[k]);
#pragma unroll
    for (int off = 32; off > 0; off >>= 1) m = fmaxf(m, __shfl_down(m, off, 64));
    if (lane == 0) red[wave] = m;
    __syncthreads();
    if (tid == 0) {
        float mm = red[0];
        for (int i = 1; i < 16; i++) mm = fmaxf(mm, red[i]);
        bcast = mm;
    }
    __syncthreads();
    const float M = bcast;

    float s = 0.0f;
    for (int k = tid; k < HID; k += 1024) s += expf(h_raw[k] - M);
    s = waveReduceSum(s);
    if (lane == 0) red[wave] = s;
    __syncthreads();
    if (tid == 0) {
        float ss = 0.0f;
        for (int i = 0; i < 16; i++) ss += red[i];
        bcast = ss;
    }
    __syncthreads();
    const float invS = 1.0f / bcast;

    for (int k = tid; k < HID; k += 1024) {
        float v = expf(h_raw[k] - M) * invS;
        h[k] = v;
        outp[(size_t)k * NSTEPS + t] = v;
    }
    if (tid < RS - HID) h[HID + tid] = 0.0f;
}

extern "C" void kernel_launch(void* const* d_in, const int* in_sizes, int n_in,
                              void* d_out, int out_size, void* d_ws, size_t ws_size,
                              hipStream_t stream)
{
    const float* x     = (const float*)d_in[0];
    const float* w_ih  = (const float*)d_in[1];
    const float* w_hh  = (const float*)d_in[2];
    const float* b_ih  = (const float*)d_in[3];
    const float* b_hh  = (const float*)d_in[4];
    const float* w_out = (const float*)d_in[5];
    const float* b_out = (const float*)d_in[6];
    float* outp = (float*)d_out;

    float* ws = (float*)d_ws;
    // small fp32 state (float offsets, all 16B aligned)
    float* h0    = ws;              // 9216
    float* c     = ws + 9216;       // 9000 (+pad)
    float* ovec  = ws + 18432;      // 512
    float* Svec  = ws + 18944;      // 128
    float* h_raw = ws + 19072;      // 9216 (fallback paths)
    float* raw3  = ws + 28288;      // 3 x RAWSTR (=960)
    float* S3    = ws + 29248;      // 3 (+pad to 192)
    float* hist  = ws + 29440;      // 20 x 9216 (ends 213760 < 262144)

    const size_t WHH_E  = (size_t)4 * HID * HID;   // 324,000,000
    const size_t WIH_E  = (size_t)4 * HID * EMB;   //  10,800,000
    const size_t WOUT_E = (size_t)EMB * HID;       //   2,700,000
    const size_t BIG_OFF = 1 << 20;                // 1 MiB: state region
    const size_t WHH4_BYTES = (size_t)4 * HID * QROW_DW * 4;  // 165,888,000
    const size_t Q4_BYTES = BIG_OFF + WHH4_BYTES + 2 * WIH_E
                          + 2 * WOUT_E + 2 * WOUT_E + 4 * (4 * (size_t)HID);
    const size_t FP16_BYTES = BIG_OFF + 2 * (WHH_E + WIH_E + WOUT_E);

    if (ws_size >= Q4_BYTES) {
        char* base = (char*)d_ws + BIG_OFF;
        uint4*  whh4i  = (uint4*)base;
        __half* wih_h  = (__half*)(base + WHH4_BYTES);
        __half* wout_h = wih_h + WIH_E;
        __half* wout_t = wout_h + WOUT_E;
        float*  wib    = (float*)(wout_t + WOUT_E);

        f32_to_f16_kernel<<<512, 256, 0, stream>>>(w_ih, wih_h, (int)(WIH_E / 8));
        f32_to_f16_kernel<<<256, 256, 0, stream>>>(w_out, wout_h, (int)(WOUT_E / 8));
        woutT_kernel<<<HID, 256, 0, stream>>>(w_out, wout_t);
        wib_kernel<<<(4 * HID + 255) / 256, 256, 0, stream>>>(
            wih_h, b_out, wib, 4 * HID);

        prime_kernel_h<<<HID, 256, 0, stream>>>(x, wih_h, b_ih, b_hh, h0, c,
                                                hist, raw3, S3);
        // t = 0: exact fp32 GEMV + int4 quantize + accumulate raw/S for t=1
        outvec_kernel_h<<<EMB, 256, 0, stream>>>(h0, wout_h, b_out, ovec, 1.0f);
        convgates_q4i4f<<<HID / 4, 256, 0, stream>>>(
            h0, ovec, w_hh, whh4i, wih_h, wout_t, b_ih, b_hh, c, hist,
            raw3 + 0 * RAWSTR, S3 + 0,            // accumulate slot 0
            raw3 + 1 * RAWSTR, S3 + 1);           // zero slot 1
        for (int t = 1; t < NSTEPS; ++t) {
            const int ri = (t - 1) % 3, wi = t % 3, zi = (t + 1) % 3;
            gates_q4i4f<<<HID / 4, 256, 0, stream>>>(
                hist + (size_t)(t - 1) * RS,
                raw3 + ri * RAWSTR, S3 + ri,
                whh4i, wih_h, wout_t, wib, b_ih, b_hh,
                c, hist + (size_t)t * RS,
                raw3 + wi * RAWSTR, S3 + wi,
                raw3 + zi * RAWSTR, S3 + zi,
                Svec, t - 1);
        }
        final_kernel<<<1, 1024, 0, stream>>>(hist, Svec, outp);
    } else if (ws_size >= FP16_BYTES) {
        __half* whh_h  = (__half*)((char*)d_ws + BIG_OFF);
        __half* wih_h  = whh_h + WHH_E;
        __half* wout_h = wih_h + WIH_E;

        f32_to_f16_kernel<<<2048, 256, 0, stream>>>(w_hh, whh_h, (int)(WHH_E / 8));
        f32_to_f16_kernel<<<512, 256, 0, stream>>>(w_ih, wih_h, (int)(WIH_E / 8));
        f32_to_f16_kernel<<<256, 256, 0, stream>>>(w_out, wout_h, (int)(WOUT_E / 8));

        prime_kernel_h<<<HID, 256, 0, stream>>>(x, wih_h, b_ih, b_hh, h0, c,
                                                hist, raw3, S3);
        for (int t = 0; t < NSTEPS; ++t) {
            outvec_kernel_h<<<EMB, 256, 0, stream>>>(h0, wout_h, b_out, ovec, 1.0f);
            gates_kernel_h<<<HID, 256, 0, stream>>>(h0, ovec, whh_h, wih_h,
                                                    b_ih, b_hh, c, h_raw);
            softmax_kernel<<<1, 1024, 0, stream>>>(h_raw, h0, outp, t);
        }
    } else {
        prime_kernel<<<HID, 256, 0, stream>>>(x, w_ih, b_ih, b_hh, h0, c);
        for (int t = 0; t < NSTEPS; ++t) {
            outvec_kernel<<<EMB, 256, 0, stream>>>(h0, w_out, b_out, ovec);
            gates_kernel<<<HID, 256, 0, stream>>>(h0, ovec, w_hh, w_ih,
                                                  b_ih, b_hh, c, h_raw);
            softmax_kernel<<<1, 1024, 0, stream>>>(h_raw, h0, outp, t);
        }
    }
}

// Round 13
// 1176.935 us; speedup vs baseline: 1.5207x; 1.5207x over previous
//
#include <hip/hip_runtime.h>
#include <hip/hip_fp16.h>
#include <math.h>

#define HID 9000
#define EMB 300
#define NSTEPS 20
#define RS 9216            // padded row stride (floats) for h0 / hist rows
#define HID8 1125          // 16B fp16 chunks per w_out/w_hh-fp16 row (9000/8)
#define EMB4 75            // 4-half chunks per w_ih row (300/4)
#define F4_ROW 2250        // valid float4 chunks per fp32 w_hh row (9000/4)
#define QROW_DW 1152       // int4 padded row: 1152 dwords (= uint4s per group)
#define QHALF 576          // dwords per half row
#define Q_D    1.4054567378526131e-3f   // int4: (1/sqrt(9000))/7.5
#define Q_INVD 711.5124735378853f       // int4: 7.5*sqrt(9000)

__device__ __forceinline__ float sigmoidf_(float v) {
    return 1.0f / (1.0f + expf(-v));
}

__device__ __forceinline__ float waveReduceSum(float v) {
#pragma unroll
    for (int off = 32; off > 0; off >>= 1) v += __shfl_down(v, off, 64);
    return v;
}

// decode one dword (8 int4, low nibble first) against 2 float4 of e,
// accumulating into TWO independent chains aA/aB
#define I4DOT8(d, v0, v1, aA, aB)                                      \
    {   unsigned int _d = (d);                                         \
        aA = fmaf((float)(((int)(_d << 28)) >> 28), v0.x, aA);         \
        aB = fmaf((float)(((int)(_d << 24)) >> 28), v0.y, aB);         \
        aA = fmaf((float)(((int)(_d << 20)) >> 28), v0.z, aA);         \
        aB = fmaf((float)(((int)(_d << 16)) >> 28), v0.w, aB);         \
        aA = fmaf((float)(((int)(_d << 12)) >> 28), v1.x, aA);         \
        aB = fmaf((float)(((int)(_d <<  8)) >> 28), v1.y, aB);         \
        aA = fmaf((float)(((int)(_d <<  4)) >> 28), v1.z, aA);         \
        aB = fmaf((float)(((int)(_d      )) >> 28), v1.w, aB); }

__device__ __forceinline__ unsigned int quant4(float v) {
    int q = (int)rintf(v * Q_INVD);
    q = q < -8 ? -8 : (q > 7 ? 7 : q);
    return (unsigned int)(q & 0xF);
}

// quantize 8 consecutive weights (two float4) into one dword, accumulate dot
__device__ __forceinline__ unsigned int qdot8(
    float4 a, float4 b, float4 h0v, float4 h1v, float& acc)
{
    acc = fmaf(a.x, h0v.x, acc);
    acc = fmaf(a.y, h0v.y, acc);
    acc = fmaf(a.z, h0v.z, acc);
    acc = fmaf(a.w, h0v.w, acc);
    acc = fmaf(b.x, h1v.x, acc);
    acc = fmaf(b.y, h1v.y, acc);
    acc = fmaf(b.z, h1v.z, acc);
    acc = fmaf(b.w, h1v.w, acc);
    return quant4(a.x)
         | (quant4(a.y) << 4)
         | (quant4(a.z) << 8)
         | (quant4(a.w) << 12)
         | (quant4(b.x) << 16)
         | (quant4(b.y) << 20)
         | (quant4(b.z) << 24)
         | (quant4(b.w) << 28);
}

// ---------------------------------------------------------------------------
// fp32 -> fp16 weight compression (w_ih, w_out).
// ---------------------------------------------------------------------------
__global__ __launch_bounds__(256) void f32_to_f16_kernel(
    const float* __restrict__ src, __half* __restrict__ dst, int n8)
{
    int i = blockIdx.x * blockDim.x + threadIdx.x;
    const int stride = gridDim.x * blockDim.x;
    const float4* __restrict__ s4 = (const float4*)src;
    float4* __restrict__ d4 = (float4*)dst;
    for (; i < n8; i += stride) {
        float4 a = s4[2 * i];
        float4 b = s4[2 * i + 1];
        float4 o;
        ((__half2*)&o)[0] = __floats2half2_rn(a.x, a.y);
        ((__half2*)&o)[1] = __floats2half2_rn(a.z, a.w);
        ((__half2*)&o)[2] = __floats2half2_rn(b.x, b.y);
        ((__half2*)&o)[3] = __floats2half2_rn(b.z, b.w);
        d4[i] = o;
    }
}

// ---------------------------------------------------------------------------
// Priming step (fp16 w_ih): h0,c = lstm_cell(x, 0, 0).
// Blocks 1..NSTEPS zero the hist-row pads [9000,9216) (ws is poisoned).
// ---------------------------------------------------------------------------
__global__ __launch_bounds__(256) void prime_kernel_h(
    const float* __restrict__ x, const __half* __restrict__ w_ih,
    const float* __restrict__ b_ih, const float* __restrict__ b_hh,
    float* __restrict__ h, float* __restrict__ c, float* __restrict__ hist)
{
    const int j = blockIdx.x;
    const int wave = threadIdx.x >> 6;
    const int lane = threadIdx.x & 63;
    const int row = j + wave * HID;
    const float2* __restrict__ wr = (const float2*)(w_ih + (size_t)row * EMB);
    const float4* __restrict__ x4 = (const float4*)x;
    float acc = 0.0f;
    for (int k = lane; k < EMB4; k += 64) {
        float2 wv = wr[k];
        const __half2* wh = (const __half2*)&wv;
        float2 w0 = __half22float2(wh[0]);
        float2 w1 = __half22float2(wh[1]);
        float4 xv = x4[k];
        acc = fmaf(w0.x, xv.x, acc);
        acc = fmaf(w0.y, xv.y, acc);
        acc = fmaf(w1.x, xv.z, acc);
        acc = fmaf(w1.y, xv.w, acc);
    }
    acc = waveReduceSum(acc);
    __shared__ float gl[4];
    if (lane == 0) gl[wave] = acc + b_ih[row] + b_hh[row];
    __syncthreads();
    if (threadIdx.x == 0) {
        float gi = gl[0], gg = gl[2], go = gl[3];
        float cn = sigmoidf_(gi) * tanhf(gg);
        float hn = sigmoidf_(go) * tanhf(cn);
        c[j] = cn;
        h[j] = hn;
    }
    if (blockIdx.x == 0 && threadIdx.x < RS - HID) h[HID + threadIdx.x] = 0.0f;
    if (blockIdx.x >= 1 && blockIdx.x <= NSTEPS && threadIdx.x < RS - HID)
        hist[(size_t)(blockIdx.x - 1) * RS + HID + threadIdx.x] = 0.0f;
}

// ---------------------------------------------------------------------------
// ovec[i] = (sum_k e_k * w_out[i,k]) / S + b_out[i]   (fp16 w_out)
// sOverride > 0: use that S (t=0, raw h). Else self-sum the input row.
// ---------------------------------------------------------------------------
__global__ __launch_bounds__(256) void outvec_kernel_h(
    const float* __restrict__ h, const __half* __restrict__ w_out,
    const float* __restrict__ b_out, float* __restrict__ ovec, float sOverride)
{
    const int i = blockIdx.x;
    const float4* __restrict__ wr = (const float4*)(w_out + (size_t)i * HID);
    const float4* __restrict__ h4 = (const float4*)h;
    const bool selfS = sOverride <= 0.0f;
    float acc = 0.0f, se = 0.0f;
    for (int k = threadIdx.x; k < HID8; k += 256) {
        float4 wv = wr[k];
        const __half2* wh = (const __half2*)&wv;
        float4 ha = h4[2 * k];
        float4 hb = h4[2 * k + 1];
        if (selfS)
            se += ((ha.x + ha.y) + (ha.z + ha.w)) + ((hb.x + hb.y) + (hb.z + hb.w));
        float2 w0 = __half22float2(wh[0]);
        float2 w1 = __half22float2(wh[1]);
        float2 w2 = __half22float2(wh[2]);
        float2 w3 = __half22float2(wh[3]);
        acc = fmaf(w0.x, ha.x, acc);
        acc = fmaf(w0.y, ha.y, acc);
        acc = fmaf(w1.x, ha.z, acc);
        acc = fmaf(w1.y, ha.w, acc);
        acc = fmaf(w2.x, hb.x, acc);
        acc = fmaf(w2.y, hb.y, acc);
        acc = fmaf(w3.x, hb.z, acc);
        acc = fmaf(w3.y, hb.w, acc);
    }
    acc = waveReduceSum(acc);
    se = waveReduceSum(se);
    __shared__ float r1[4], r2[4];
    const int wave = threadIdx.x >> 6;
    const int lane = threadIdx.x & 63;
    if (lane == 0) { r1[wave] = acc; r2[wave] = se; }
    __syncthreads();
    if (threadIdx.x == 0) {
        float S = selfS ? ((r2[0] + r2[1]) + (r2[2] + r2[3])) : sOverride;
        ovec[i] = ((r1[0] + r1[1]) + (r1[2] + r1[3])) / S + b_out[i];
    }
}

// ---------------------------------------------------------------------------
// Fused t=0: exact fp32 w_hh GEMV + int4 quantize into the 4-j INTERLEAVED
// layout: uint4 W[(jq*4 + p*2 + g01)*QROW_DW + ci] = dword ci of w_hh rows
// {(2p+g01)*HID + j0+0, +1, +2, +3} in .x/.y/.z/.w, j0 = 4*jq.
// Block = j quad; wave (p, hf) covers ci in [hf*576, hf*576+576).
// Epilogue: c update, e0 = exp(h_new) -> hist row 0 (all 4 j).
// ---------------------------------------------------------------------------
__global__ __launch_bounds__(256) void convgates_q4i4(
    const float* __restrict__ h, const float* __restrict__ ovec,
    const float* __restrict__ w_hh, uint4* __restrict__ whh4i,
    const __half* __restrict__ w_ih,
    const float* __restrict__ b_ih, const float* __restrict__ b_hh,
    float* __restrict__ c, float* __restrict__ e_out)
{
    const int jq = blockIdx.x;
    const int j0 = jq * 4;
    const int wave = threadIdx.x >> 6;
    const int lane = threadIdx.x & 63;
    const int pair = wave >> 1;      // gate pair {2p, 2p+1}
    const int half = wave & 1;       // k-half of the row

    const float4* __restrict__ wA0 =
        (const float4*)(w_hh + (size_t)(2 * pair * HID + j0) * HID);
    const float4* __restrict__ wA1 = wA0 + F4_ROW;
    const float4* __restrict__ wA2 = wA1 + F4_ROW;
    const float4* __restrict__ wA3 = wA2 + F4_ROW;
    const float4* __restrict__ wB0 =
        (const float4*)(w_hh + (size_t)((2 * pair + 1) * HID + j0) * HID);
    const float4* __restrict__ wB1 = wB0 + F4_ROW;
    const float4* __restrict__ wB2 = wB1 + F4_ROW;
    const float4* __restrict__ wB3 = wB2 + F4_ROW;
    uint4* __restrict__ dst0 = whh4i + (size_t)(jq * 4 + pair * 2 + 0) * QROW_DW;
    uint4* __restrict__ dst1 = whh4i + (size_t)(jq * 4 + pair * 2 + 1) * QROW_DW;
    const float4* __restrict__ h4 = (const float4*)h;

    float aA0 = 0.0f, aA1 = 0.0f, aA2 = 0.0f, aA3 = 0.0f;
    float aB0 = 0.0f, aB1 = 0.0f, aB2 = 0.0f, aB3 = 0.0f;
    const int base = half * QHALF;
    for (int it = 0; it < 9; ++it) {
        const int ci = base + it * 64 + lane;   // dword index, 0..1151
        uint4 p0, p1;
        p0.x = p0.y = p0.z = p0.w = 0u;
        p1.x = p1.y = p1.z = p1.w = 0u;
        if (ci < HID8) {                        // 1125 real dwords per row
            float4 hv0 = h4[2 * ci];
            float4 hv1 = h4[2 * ci + 1];
            p0.x = qdot8(wA0[2 * ci], wA0[2 * ci + 1], hv0, hv1, aA0);
            p0.y = qdot8(wA1[2 * ci], wA1[2 * ci + 1], hv0, hv1, aA1);
            p0.z = qdot8(wA2[2 * ci], wA2[2 * ci + 1], hv0, hv1, aA2);
            p0.w = qdot8(wA3[2 * ci], wA3[2 * ci + 1], hv0, hv1, aA3);
            p1.x = qdot8(wB0[2 * ci], wB0[2 * ci + 1], hv0, hv1, aB0);
            p1.y = qdot8(wB1[2 * ci], wB1[2 * ci + 1], hv0, hv1, aB1);
            p1.z = qdot8(wB2[2 * ci], wB2[2 * ci + 1], hv0, hv1, aB2);
            p1.w = qdot8(wB3[2 * ci], wB3[2 * ci + 1], hv0, hv1, aB3);
        }
        dst0[ci] = p0;                          // pads get 0 (decode -> q=0)
        dst1[ci] = p1;
    }

    // w_ih (fp16) @ ovec for gate row = wave, all 4 j
    const int row0 = j0 + wave * HID;
    float ai0 = 0.0f, ai1 = 0.0f, ai2 = 0.0f, ai3 = 0.0f;
    const float2* __restrict__ wir0 = (const float2*)(w_ih + (size_t)row0 * EMB);
    const float2* __restrict__ wir1 = wir0 + EMB / 2;
    const float2* __restrict__ wir2 = wir1 + EMB / 2;
    const float2* __restrict__ wir3 = wir2 + EMB / 2;
    const float4* __restrict__ o4 = (const float4*)ovec;
    for (int k = lane; k < EMB4; k += 64) {
        float4 ov = o4[k];
        float2 wv0 = wir0[k];
        float2 wv1 = wir1[k];
        float2 wv2 = wir2[k];
        float2 wv3 = wir3[k];
        const __half2* q0 = (const __half2*)&wv0;
        const __half2* q1 = (const __half2*)&wv1;
        const __half2* q2 = (const __half2*)&wv2;
        const __half2* q3 = (const __half2*)&wv3;
        float2 a0 = __half22float2(q0[0]), a1 = __half22float2(q0[1]);
        float2 b0 = __half22float2(q1[0]), b1 = __half22float2(q1[1]);
        float2 c0 = __half22float2(q2[0]), c1 = __half22float2(q2[1]);
        float2 d0 = __half22float2(q3[0]), d1 = __half22float2(q3[1]);
        ai0 = fmaf(a0.x, ov.x, ai0); ai0 = fmaf(a0.y, ov.y, ai0);
        ai0 = fmaf(a1.x, ov.z, ai0); ai0 = fmaf(a1.y, ov.w, ai0);
        ai1 = fmaf(b0.x, ov.x, ai1); ai1 = fmaf(b0.y, ov.y, ai1);
        ai1 = fmaf(b1.x, ov.z, ai1); ai1 = fmaf(b1.y, ov.w, ai1);
        ai2 = fmaf(c0.x, ov.x, ai2); ai2 = fmaf(c0.y, ov.y, ai2);
        ai2 = fmaf(c1.x, ov.z, ai2); ai2 = fmaf(c1.y, ov.w, ai2);
        ai3 = fmaf(d0.x, ov.x, ai3); ai3 = fmaf(d0.y, ov.y, ai3);
        ai3 = fmaf(d1.x, ov.z, ai3); ai3 = fmaf(d1.y, ov.w, ai3);
    }

    aA0 = waveReduceSum(aA0); aA1 = waveReduceSum(aA1);
    aA2 = waveReduceSum(aA2); aA3 = waveReduceSum(aA3);
    aB0 = waveReduceSum(aB0); aB1 = waveReduceSum(aB1);
    aB2 = waveReduceSum(aB2); aB3 = waveReduceSum(aB3);
    ai0 = waveReduceSum(ai0); ai1 = waveReduceSum(ai1);
    ai2 = waveReduceSum(ai2); ai3 = waveReduceSum(ai3);

    __shared__ float gq[4][4][2];   // [wave][jj][g01] exact dot partials
    __shared__ float gih[4][4];     // [gate][jj] w_ih dot + biases
    if (lane == 0) {
        gq[wave][0][0] = aA0; gq[wave][1][0] = aA1;
        gq[wave][2][0] = aA2; gq[wave][3][0] = aA3;
        gq[wave][0][1] = aB0; gq[wave][1][1] = aB1;
        gq[wave][2][1] = aB2; gq[wave][3][1] = aB3;
        gih[wave][0] = ai0 + b_ih[row0] + b_hh[row0];
        gih[wave][1] = ai1 + b_ih[row0 + 1] + b_hh[row0 + 1];
        gih[wave][2] = ai2 + b_ih[row0 + 2] + b_hh[row0 + 2];
        gih[wave][3] = ai3 + b_ih[row0 + 3] + b_hh[row0 + 3];
    }
    __syncthreads();
    if (threadIdx.x < 4) {
        const int jj = threadIdx.x;
        const int j = j0 + jj;
        float gi = (gq[0][jj][0] + gq[1][jj][0]) + gih[0][jj];
        float gf = (gq[0][jj][1] + gq[1][jj][1]) + gih[1][jj];
        float gg = (gq[2][jj][0] + gq[3][jj][0]) + gih[2][jj];
        float go = (gq[2][jj][1] + gq[3][jj][1]) + gih[3][jj];
        float cp = c[j];
        float cn = sigmoidf_(gf) * cp + sigmoidf_(gi) * tanhf(gg);
        float hn = sigmoidf_(go) * tanhf(cn);
        c[j] = cn;
        e_out[j] = expf(hn);   // |hn| < 1 -> exp safe without max-shift
    }
}

// ---------------------------------------------------------------------------
// Steady-state gates (t>=1): 4-j interleaved int4 w_hh. Block = j quad; wave
// (p, hf) reads TWO uint4 per lane-iter (gates 2p and 2p+1, each covering
// j0..j0+3) + 2 contiguous float4 of e (32B weights : 32B e). 9 exact iters.
// Cross-wave combine via LDS; unnormalized e input, 1/S folded in epilogue.
// ---------------------------------------------------------------------------
__global__ __launch_bounds__(256) void gates_q4i4(
    const float* __restrict__ e_in, const float* __restrict__ ovec,
    const uint4* __restrict__ whh4i, const __half* __restrict__ w_ih,
    const float* __restrict__ b_ih, const float* __restrict__ b_hh,
    float* __restrict__ c, float* __restrict__ e_out,
    float* __restrict__ Svec, int tm1)
{
    const int jq = blockIdx.x;
    const int j0 = jq * 4;
    const int wave = threadIdx.x >> 6;
    const int lane = threadIdx.x & 63;
    const int pair = wave >> 1;      // gate pair {2p, 2p+1}
    const int half = wave & 1;       // k-half of the row

    const uint4* __restrict__ g0 = whh4i + (size_t)(jq * 4 + pair * 2 + 0) * QROW_DW;
    const uint4* __restrict__ g1 = whh4i + (size_t)(jq * 4 + pair * 2 + 1) * QROW_DW;
    const float4* __restrict__ e4 = (const float4*)e_in;

    float A0a = 0.0f, A0b = 0.0f, A1a = 0.0f, A1b = 0.0f;
    float A2a = 0.0f, A2b = 0.0f, A3a = 0.0f, A3b = 0.0f;
    float B0a = 0.0f, B0b = 0.0f, B1a = 0.0f, B1b = 0.0f;
    float B2a = 0.0f, B2b = 0.0f, B3a = 0.0f, B3b = 0.0f;
    float se = 0.0f;
    const int base = half * QHALF;
#pragma unroll 3
    for (int it = 0; it < 9; ++it) {
        const int ci = base + it * 64 + lane;   // dword index, 0..1151
        uint4 w0 = g0[ci];
        uint4 w1 = g1[ci];
        float4 ev0 = e4[2 * ci];
        float4 ev1 = e4[2 * ci + 1];
        if (pair == 0)
            se += ((ev0.x + ev0.y) + (ev0.z + ev0.w))
                + ((ev1.x + ev1.y) + (ev1.z + ev1.w));
        I4DOT8(w0.x, ev0, ev1, A0a, A0b);   // gate 2p,   j0
        I4DOT8(w0.y, ev0, ev1, A1a, A1b);   // gate 2p,   j0+1
        I4DOT8(w0.z, ev0, ev1, A2a, A2b);   // gate 2p,   j0+2
        I4DOT8(w0.w, ev0, ev1, A3a, A3b);   // gate 2p,   j0+3
        I4DOT8(w1.x, ev0, ev1, B0a, B0b);   // gate 2p+1, j0
        I4DOT8(w1.y, ev0, ev1, B1a, B1b);   // gate 2p+1, j0+1
        I4DOT8(w1.z, ev0, ev1, B2a, B2b);   // gate 2p+1, j0+2
        I4DOT8(w1.w, ev0, ev1, B3a, B3b);   // gate 2p+1, j0+3
    }
    float pA0 = A0a + A0b, pA1 = A1a + A1b, pA2 = A2a + A2b, pA3 = A3a + A3b;
    float pB0 = B0a + B0b, pB1 = B1a + B1b, pB2 = B2a + B2b, pB3 = B3a + B3b;

    // w_ih (fp16) @ ovec for THIS wave's gate (gate index == wave), all 4 j
    const int row0 = j0 + wave * HID;
    float ai0 = 0.0f, ai1 = 0.0f, ai2 = 0.0f, ai3 = 0.0f;
    const float2* __restrict__ wir0 = (const float2*)(w_ih + (size_t)row0 * EMB);
    const float2* __restrict__ wir1 = wir0 + EMB / 2;
    const float2* __restrict__ wir2 = wir1 + EMB / 2;
    const float2* __restrict__ wir3 = wir2 + EMB / 2;
    const float4* __restrict__ o4 = (const float4*)ovec;
    for (int k = lane; k < EMB4; k += 64) {
        float4 ov = o4[k];
        float2 wv0 = wir0[k];
        float2 wv1 = wir1[k];
        float2 wv2 = wir2[k];
        float2 wv3 = wir3[k];
        const __half2* q0 = (const __half2*)&wv0;
        const __half2* q1 = (const __half2*)&wv1;
        const __half2* q2 = (const __half2*)&wv2;
        const __half2* q3 = (const __half2*)&wv3;
        float2 a0 = __half22float2(q0[0]), a1 = __half22float2(q0[1]);
        float2 b0 = __half22float2(q1[0]), b1 = __half22float2(q1[1]);
        float2 c0 = __half22float2(q2[0]), c1 = __half22float2(q2[1]);
        float2 d0 = __half22float2(q3[0]), d1 = __half22float2(q3[1]);
        ai0 = fmaf(a0.x, ov.x, ai0); ai0 = fmaf(a0.y, ov.y, ai0);
        ai0 = fmaf(a1.x, ov.z, ai0); ai0 = fmaf(a1.y, ov.w, ai0);
        ai1 = fmaf(b0.x, ov.x, ai1); ai1 = fmaf(b0.y, ov.y, ai1);
        ai1 = fmaf(b1.x, ov.z, ai1); ai1 = fmaf(b1.y, ov.w, ai1);
        ai2 = fmaf(c0.x, ov.x, ai2); ai2 = fmaf(c0.y, ov.y, ai2);
        ai2 = fmaf(c1.x, ov.z, ai2); ai2 = fmaf(c1.y, ov.w, ai2);
        ai3 = fmaf(d0.x, ov.x, ai3); ai3 = fmaf(d0.y, ov.y, ai3);
        ai3 = fmaf(d1.x, ov.z, ai3); ai3 = fmaf(d1.y, ov.w, ai3);
    }

    pA0 = waveReduceSum(pA0); pA1 = waveReduceSum(pA1);
    pA2 = waveReduceSum(pA2); pA3 = waveReduceSum(pA3);
    pB0 = waveReduceSum(pB0); pB1 = waveReduceSum(pB1);
    pB2 = waveReduceSum(pB2); pB3 = waveReduceSum(pB3);
    ai0 = waveReduceSum(ai0); ai1 = waveReduceSum(ai1);
    ai2 = waveReduceSum(ai2); ai3 = waveReduceSum(ai3);
    if (pair == 0) se = waveReduceSum(se);

    __shared__ float gq[4][4][2];   // [wave][jj][g01] int4-dot partials
    __shared__ float gih[4][4];     // [gate][jj] w_ih dot + biases
    __shared__ float sp[2];         // e-sum halves (waves 0,1)
    if (lane == 0) {
        gq[wave][0][0] = pA0; gq[wave][1][0] = pA1;
        gq[wave][2][0] = pA2; gq[wave][3][0] = pA3;
        gq[wave][0][1] = pB0; gq[wave][1][1] = pB1;
        gq[wave][2][1] = pB2; gq[wave][3][1] = pB3;
        gih[wave][0] = ai0 + b_ih[row0] + b_hh[row0];
        gih[wave][1] = ai1 + b_ih[row0 + 1] + b_hh[row0 + 1];
        gih[wave][2] = ai2 + b_ih[row0 + 2] + b_hh[row0 + 2];
        gih[wave][3] = ai3 + b_ih[row0 + 3] + b_hh[row0 + 3];
        if (pair == 0) sp[half] = se;
    }
    __syncthreads();
    if (threadIdx.x < 4) {
        const int jj = threadIdx.x;
        const int j = j0 + jj;
        const float S = sp[0] + sp[1];
        const float scale = Q_D / S;
        float gi = (gq[0][jj][0] + gq[1][jj][0]) * scale + gih[0][jj];
        float gf = (gq[0][jj][1] + gq[1][jj][1]) * scale + gih[1][jj];
        float gg = (gq[2][jj][0] + gq[3][jj][0]) * scale + gih[2][jj];
        float go = (gq[2][jj][1] + gq[3][jj][1]) * scale + gih[3][jj];
        float cp = c[j];
        float cn = sigmoidf_(gf) * cp + sigmoidf_(gi) * tanhf(gg);
        float hn = sigmoidf_(go) * tanhf(cn);
        c[j] = cn;
        e_out[j] = expf(hn);
        if (blockIdx.x == 0 && jj == 0) Svec[tm1] = S;  // S of INPUT row (t-1)
    }
}

// ---------------------------------------------------------------------------
// Final: compute S_19, then outp[k*NSTEPS+t] = hist[t][k] / S_t (coalesced).
// ---------------------------------------------------------------------------
__global__ __launch_bounds__(1024) void final_kernel(
    const float* __restrict__ hist, const float* __restrict__ Svec,
    float* __restrict__ outp)
{
    __shared__ float red[16];
    __shared__ float invSl[NSTEPS];
    const int tid = threadIdx.x;
    const int wave = tid >> 6;
    const int lane = tid & 63;

    float s = 0.0f;
    for (int k = tid; k < HID; k += 1024) s += hist[(size_t)(NSTEPS - 1) * RS + k];
    s = waveReduceSum(s);
    if (lane == 0) red[wave] = s;
    __syncthreads();
    if (tid == 0) {
        float s19 = 0.0f;
        for (int i = 0; i < 16; i++) s19 += red[i];
        red[0] = s19;
    }
    __syncthreads();
    if (tid < NSTEPS) invSl[tid] = 1.0f / ((tid == NSTEPS - 1) ? red[0] : Svec[tid]);
    __syncthreads();

    for (int k = tid; k < HID; k += 1024) {
        float o[NSTEPS];
#pragma unroll
        for (int t = 0; t < NSTEPS; t++) o[t] = hist[(size_t)t * RS + k] * invSl[t];
        float4* dst = (float4*)(outp + (size_t)k * NSTEPS);
#pragma unroll
        for (int q = 0; q < 5; q++)
            dst[q] = make_float4(o[4 * q], o[4 * q + 1], o[4 * q + 2], o[4 * q + 3]);
    }
}

// ===========================================================================
// fp16 / fp32 fallback kernels
// ===========================================================================
__global__ __launch_bounds__(256) void gates_kernel_h(
    const float* __restrict__ h, const float* __restrict__ ovec,
    const __half* __restrict__ w_hh, const __half* __restrict__ w_ih,
    const float* __restrict__ b_ih, const float* __restrict__ b_hh,
    float* __restrict__ c, float* __restrict__ h_raw)
{
    const int j = blockIdx.x;
    const int wave = threadIdx.x >> 6;
    const int lane = threadIdx.x & 63;
    const int row = j + wave * HID;

    const float4* __restrict__ wr = (const float4*)(w_hh + (size_t)row * HID);
    const float4* __restrict__ h4 = (const float4*)h;
    float acc = 0.0f;
    for (int k = lane; k < HID8; k += 64) {
        float4 wv = wr[k];
        const __half2* wh = (const __half2*)&wv;
        float4 ha = h4[2 * k];
        float4 hb = h4[2 * k + 1];
        float2 w0 = __half22float2(wh[0]);
        float2 w1 = __half22float2(wh[1]);
        float2 w2 = __half22float2(wh[2]);
        float2 w3 = __half22float2(wh[3]);
        acc = fmaf(w0.x, ha.x, acc);
        acc = fmaf(w0.y, ha.y, acc);
        acc = fmaf(w1.x, ha.z, acc);
        acc = fmaf(w1.y, ha.w, acc);
        acc = fmaf(w2.x, hb.x, acc);
        acc = fmaf(w2.y, hb.y, acc);
        acc = fmaf(w3.x, hb.z, acc);
        acc = fmaf(w3.y, hb.w, acc);
    }
    const float2* __restrict__ wir = (const float2*)(w_ih + (size_t)row * EMB);
    const float4* __restrict__ o4 = (const float4*)ovec;
    for (int k = lane; k < EMB4; k += 64) {
        float2 wv = wir[k];
        const __half2* wh = (const __half2*)&wv;
        float2 w0 = __half22float2(wh[0]);
        float2 w1 = __half22float2(wh[1]);
        float4 ov = o4[k];
        acc = fmaf(w0.x, ov.x, acc);
        acc = fmaf(w0.y, ov.y, acc);
        acc = fmaf(w1.x, ov.z, acc);
        acc = fmaf(w1.y, ov.w, acc);
    }
    acc = waveReduceSum(acc);
    __shared__ float gl[4];
    if (lane == 0) gl[wave] = acc + b_ih[row] + b_hh[row];
    __syncthreads();
    if (threadIdx.x == 0) {
        float gi = gl[0], gf = gl[1], gg = gl[2], go = gl[3];
        float cp = c[j];
        float cn = sigmoidf_(gf) * cp + sigmoidf_(gi) * tanhf(gg);
        float hn = sigmoidf_(go) * tanhf(cn);
        c[j] = cn;
        h_raw[j] = hn;
    }
}

__global__ __launch_bounds__(256) void prime_kernel(
    const float* __restrict__ x, const float* __restrict__ w_ih,
    const float* __restrict__ b_ih, const float* __restrict__ b_hh,
    float* __restrict__ h, float* __restrict__ c)
{
    const int j = blockIdx.x;
    const int wave = threadIdx.x >> 6;
    const int lane = threadIdx.x & 63;
    const int row = j + wave * HID;
    const float4* __restrict__ wr = (const float4*)(w_ih + (size_t)row * EMB);
    const float4* __restrict__ x4 = (const float4*)x;
    float acc = 0.0f;
    for (int k = lane; k < EMB / 4; k += 64) {
        float4 w = wr[k];
        float4 xv = x4[k];
        acc = fmaf(w.x, xv.x, acc);
        acc = fmaf(w.y, xv.y, acc);
        acc = fmaf(w.z, xv.z, acc);
        acc = fmaf(w.w, xv.w, acc);
    }
    acc = waveReduceSum(acc);
    __shared__ float gl[4];
    if (lane == 0) gl[wave] = acc + b_ih[row] + b_hh[row];
    __syncthreads();
    if (threadIdx.x == 0) {
        float gi = gl[0], gg = gl[2], go = gl[3];
        float cn = sigmoidf_(gi) * tanhf(gg);
        float hn = sigmoidf_(go) * tanhf(cn);
        c[j] = cn;
        h[j] = hn;
    }
    if (blockIdx.x == 0 && threadIdx.x < RS - HID) h[HID + threadIdx.x] = 0.0f;
}

__global__ __launch_bounds__(256) void outvec_kernel(
    const float* __restrict__ h, const float* __restrict__ w_out,
    const float* __restrict__ b_out, float* __restrict__ ovec)
{
    const int i = blockIdx.x;
    const float4* __restrict__ wr = (const float4*)(w_out + (size_t)i * HID);
    const float4* __restrict__ h4 = (const float4*)h;
    float acc = 0.0f;
    for (int k = threadIdx.x; k < HID / 4; k += 256) {
        float4 w = wr[k];
        float4 hv = h4[k];
        acc = fmaf(w.x, hv.x, acc);
        acc = fmaf(w.y, hv.y, acc);
        acc = fmaf(w.z, hv.z, acc);
        acc = fmaf(w.w, hv.w, acc);
    }
    acc = waveReduceSum(acc);
    __shared__ float red[4];
    const int wave = threadIdx.x >> 6;
    const int lane = threadIdx.x & 63;
    if (lane == 0) red[wave] = acc;
    __syncthreads();
    if (threadIdx.x == 0)
        ovec[i] = red[0] + red[1] + red[2] + red[3] + b_out[i];
}

__global__ __launch_bounds__(256) void gates_kernel(
    const float* __restrict__ h, const float* __restrict__ ovec,
    const float* __restrict__ w_hh, const float* __restrict__ w_ih,
    const float* __restrict__ b_ih, const float* __restrict__ b_hh,
    float* __restrict__ c, float* __restrict__ h_raw)
{
    const int j = blockIdx.x;
    const int wave = threadIdx.x >> 6;
    const int lane = threadIdx.x & 63;
    const int row = j + wave * HID;

    const float4* __restrict__ wr = (const float4*)(w_hh + (size_t)row * HID);
    const float4* __restrict__ h4 = (const float4*)h;
    float acc = 0.0f;
    for (int k = lane; k < HID / 4; k += 64) {
        float4 w = wr[k];
        float4 hv = h4[k];
        acc = fmaf(w.x, hv.x, acc);
        acc = fmaf(w.y, hv.y, acc);
        acc = fmaf(w.z, hv.z, acc);
        acc = fmaf(w.w, hv.w, acc);
    }
    const float4* __restrict__ wir = (const float4*)(w_ih + (size_t)row * EMB);
    const float4* __restrict__ o4 = (const float4*)ovec;
    for (int k = lane; k < EMB / 4; k += 64) {
        float4 w = wir[k];
        float4 ov = o4[k];
        acc = fmaf(w.x, ov.x, acc);
        acc = fmaf(w.y, ov.y, acc);
        acc = fmaf(w.z, ov.z, acc);
        acc = fmaf(w.w, ov.w, acc);
    }
    acc = waveReduceSum(acc);
    __shared__ float gl[4];
    if (lane == 0) gl[wave] = acc + b_ih[row] + b_hh[row];
    __syncthreads();
    if (threadIdx.x == 0) {
        float gi = gl[0], gf = gl[1], gg = gl[2], go = gl[3];
        float cp = c[j];
        float cn = sigmoidf_(gf) * cp + sigmoidf_(gi) * tanhf(gg);
        float hn = sigmoidf_(go) * tanhf(cn);
        c[j] = cn;
        h_raw[j] = hn;
    }
}

__global__ __launch_bounds__(1024) void softmax_kernel(
    const float* __restrict__ h_raw, float* __restrict__ h,
    float* __restrict__ outp, int t)
{
    __shared__ float red[16];
    __shared__ float bcast;
    const int tid = threadIdx.x;
    const int wave = tid >> 6;
    const int lane = tid & 63;

    float m = -INFINITY;
    for (int k = tid; k < HID; k += 1024) m = fmaxf(m, h_raw[k]);
#pragma unroll
    for (int off = 32; off > 0; off >>= 1) m = fmaxf(m, __shfl_down(m, off, 64));
    if (lane == 0) red[wave] = m;
    __syncthreads();
    if (tid == 0) {
        float mm = red[0];
        for (int i = 1; i < 16; i++) mm = fmaxf(mm, red[i]);
        bcast = mm;
    }
    __syncthreads();
    const float M = bcast;

    float s = 0.0f;
    for (int k = tid; k < HID; k += 1024) s += expf(h_raw[k] - M);
    s = waveReduceSum(s);
    if (lane == 0) red[wave] = s;
    __syncthreads();
    if (tid == 0) {
        float ss = 0.0f;
        for (int i = 0; i < 16; i++) ss += red[i];
        bcast = ss;
    }
    __syncthreads();
    const float invS = 1.0f / bcast;

    for (int k = tid; k < HID; k += 1024) {
        float v = expf(h_raw[k] - M) * invS;
        h[k] = v;
        outp[(size_t)k * NSTEPS + t] = v;
    }
    if (tid < RS - HID) h[HID + tid] = 0.0f;
}

extern "C" void kernel_launch(void* const* d_in, const int* in_sizes, int n_in,
                              void* d_out, int out_size, void* d_ws, size_t ws_size,
                              hipStream_t stream)
{
    const float* x     = (const float*)d_in[0];
    const float* w_ih  = (const float*)d_in[1];
    const float* w_hh  = (const float*)d_in[2];
    const float* b_ih  = (const float*)d_in[3];
    const float* b_hh  = (const float*)d_in[4];
    const float* w_out = (const float*)d_in[5];
    const float* b_out = (const float*)d_in[6];
    float* outp = (float*)d_out;

    float* ws = (float*)d_ws;
    // small fp32 state (float offsets, all 16B aligned)
    float* h0    = ws;             // 9216
    float* c     = ws + 9216;      // 9000 (+pad)
    float* ovec  = ws + 18432;     // 300 (+pad)
    float* Svec  = ws + 18944;     // 20 (+pad)
    float* h_raw = ws + 19072;     // 9000 (fallback paths)
    float* hist  = ws + 28288;     // 20 x 9216

    const size_t WHH_E  = (size_t)4 * HID * HID;   // 324,000,000
    const size_t WIH_E  = (size_t)4 * HID * EMB;   //  10,800,000
    const size_t WOUT_E = (size_t)EMB * HID;       //   2,700,000
    const size_t BIG_OFF = 1 << 20;                // 1 MiB: state region
    const size_t WHH4_BYTES = (size_t)4 * HID * QROW_DW * 4;  // 165,888,000
    const size_t Q4_BYTES   = BIG_OFF + WHH4_BYTES + 2 * (WIH_E + WOUT_E);
    const size_t FP16_BYTES = BIG_OFF + 2 * (WHH_E + WIH_E + WOUT_E);

    if (ws_size >= Q4_BYTES) {
        uint4* whh4i  = (uint4*)((char*)d_ws + BIG_OFF);
        __half* wih_h  = (__half*)((char*)d_ws + BIG_OFF + WHH4_BYTES);
        __half* wout_h = wih_h + WIH_E;

        f32_to_f16_kernel<<<512, 256, 0, stream>>>(w_ih, wih_h, (int)(WIH_E / 8));
        f32_to_f16_kernel<<<256, 256, 0, stream>>>(w_out, wout_h, (int)(WOUT_E / 8));

        prime_kernel_h<<<HID, 256, 0, stream>>>(x, wih_h, b_ih, b_hh, h0, c, hist);
        // t = 0: exact fp32 GEMV fused with 4-j interleaved int4 quantization
        outvec_kernel_h<<<EMB, 256, 0, stream>>>(h0, wout_h, b_out, ovec, 1.0f);
        convgates_q4i4<<<HID / 4, 256, 0, stream>>>(h0, ovec, w_hh, whh4i, wih_h,
                                                    b_ih, b_hh, c, hist);
        for (int t = 1; t < NSTEPS; ++t) {
            outvec_kernel_h<<<EMB, 256, 0, stream>>>(
                hist + (size_t)(t - 1) * RS, wout_h, b_out, ovec, -1.0f);
            gates_q4i4<<<HID / 4, 256, 0, stream>>>(
                hist + (size_t)(t - 1) * RS, ovec, whh4i, wih_h,
                b_ih, b_hh, c, hist + (size_t)t * RS, Svec, t - 1);
        }
        final_kernel<<<1, 1024, 0, stream>>>(hist, Svec, outp);
    } else if (ws_size >= FP16_BYTES) {
        __half* whh_h  = (__half*)((char*)d_ws + BIG_OFF);
        __half* wih_h  = whh_h + WHH_E;
        __half* wout_h = wih_h + WIH_E;

        f32_to_f16_kernel<<<2048, 256, 0, stream>>>(w_hh, whh_h, (int)(WHH_E / 8));
        f32_to_f16_kernel<<<512, 256, 0, stream>>>(w_ih, wih_h, (int)(WIH_E / 8));
        f32_to_f16_kernel<<<256, 256, 0, stream>>>(w_out, wout_h, (int)(WOUT_E / 8));

        prime_kernel_h<<<HID, 256, 0, stream>>>(x, wih_h, b_ih, b_hh, h0, c, hist);
        for (int t = 0; t < NSTEPS; ++t) {
            outvec_kernel_h<<<EMB, 256, 0, stream>>>(h0, wout_h, b_out, ovec, 1.0f);
            gates_kernel_h<<<HID, 256, 0, stream>>>(h0, ovec, whh_h, wih_h,
                                                    b_ih, b_hh, c, h_raw);
            softmax_kernel<<<1, 1024, 0, stream>>>(h_raw, h0, outp, t);
        }
    } else {
        prime_kernel<<<HID, 256, 0, stream>>>(x, w_ih, b_ih, b_hh, h0, c);
        for (int t = 0; t < NSTEPS; ++t) {
            outvec_kernel<<<EMB, 256, 0, stream>>>(h0, w_out, b_out, ovec);
            gates_kernel<<<HID, 256, 0, stream>>>(h0, ovec, w_hh, w_ih,
                                                  b_ih, b_hh, c, h_raw);
            softmax_kernel<<<1, 1024, 0, stream>>>(h_raw, h0, outp, t);
        }
    }
}